// Round 1
// 740.211 us; speedup vs baseline: 1.0514x; 1.0514x over previous
//
#include <hip/hip_runtime.h>

#define DD 128
#define TILE_E 64

typedef __attribute__((ext_vector_type(8))) short short8;
typedef __attribute__((ext_vector_type(4))) float f32x4;

__device__ __forceinline__ unsigned short f2bf(float f) {
  unsigned int u = __float_as_uint(f);
  u += 0x7FFF + ((u >> 16) & 1);   // RNE
  return (unsigned short)(u >> 16);
}

// ---- Phase A: build dest-sorted edge list (replaces 64M fp32 atomics) ----

__global__ __launch_bounds__(256) void hist_kernel(
    const int* __restrict__ eidx, int* __restrict__ cnt, int E) {
  int e = blockIdx.x * 256 + threadIdx.x;
  if (e < E) atomicAdd(&cnt[eidx[E + e]], 1);
}

// single-block exclusive scan over V counts -> off, and copy -> cur
__global__ __launch_bounds__(1024) void scan_kernel(
    const int* __restrict__ cnt, int* __restrict__ off, int* __restrict__ cur, int V) {
  __shared__ int s[1024];
  const int t = threadIdx.x;
  const int chunk = (V + 1023) / 1024;
  const int lo = t * chunk, hi = min(lo + chunk, V);
  int tot = 0;
  for (int v = lo; v < hi; ++v) tot += cnt[v];
  s[t] = tot;
  __syncthreads();
  // Hillis-Steele inclusive scan of thread totals
  for (int d = 1; d < 1024; d <<= 1) {
    int x = (t >= d) ? s[t - d] : 0;
    __syncthreads();
    s[t] += x;
    __syncthreads();
  }
  int run = (t > 0) ? s[t - 1] : 0;
  for (int v = lo; v < hi; ++v) {
    off[v] = run; cur[v] = run;
    run += cnt[v];
  }
}

__global__ __launch_bounds__(256) void fill_kernel(
    const int* __restrict__ eidx, int* __restrict__ cur,
    int* __restrict__ elist, int E) {
  int e = blockIdx.x * 256 + threadIdx.x;
  if (e < E) {
    int p = atomicAdd(&cur[eidx[E + e]], 1);
    elist[p] = e;
  }
}

// ---- Phase B: nm[v,:] = sum_{e: dest[e]=v} relu(ef[e,:])  (one wave per node) ----
// unroll-4: keep 4 independent 512B rows in flight per wave to hide HBM latency
__global__ __launch_bounds__(256) void gather_sum_kernel(
    const float* __restrict__ ef, const int* __restrict__ off,
    const int* __restrict__ cnt, const int* __restrict__ elist,
    float* __restrict__ nm, int V) {
  const int lane = threadIdx.x & 63;
  const int v = blockIdx.x * 4 + (threadIdx.x >> 6);
  if (v >= V) return;
  const int base = off[v];
  const int deg  = cnt[v];
  float2 acc0 = make_float2(0.f, 0.f);
  float2 acc1 = make_float2(0.f, 0.f);
  int j = 0;
  for (; j + 4 <= deg; j += 4) {
    int ea = elist[base + j + 0];
    int eb = elist[base + j + 1];
    int ec = elist[base + j + 2];
    int ed = elist[base + j + 3];
    float2 ma = ((const float2*)(ef + (size_t)ea * DD))[lane];
    float2 mb = ((const float2*)(ef + (size_t)eb * DD))[lane];
    float2 mc = ((const float2*)(ef + (size_t)ec * DD))[lane];
    float2 md = ((const float2*)(ef + (size_t)ed * DD))[lane];
    acc0.x += fmaxf(ma.x, 0.f) + fmaxf(mb.x, 0.f);
    acc0.y += fmaxf(ma.y, 0.f) + fmaxf(mb.y, 0.f);
    acc1.x += fmaxf(mc.x, 0.f) + fmaxf(md.x, 0.f);
    acc1.y += fmaxf(mc.y, 0.f) + fmaxf(md.y, 0.f);
  }
  for (; j < deg; ++j) {
    int e = elist[base + j];
    float2 m = ((const float2*)(ef + (size_t)e * DD))[lane];
    acc0.x += fmaxf(m.x, 0.f);
    acc0.y += fmaxf(m.y, 0.f);
  }
  ((float2*)(nm + (size_t)v * DD))[lane] =
      make_float2(acc0.x + acc1.x, acc0.y + acc1.y);
}

// ---- W -> bf16 fragment-major precompute (once per launch) ----
// Wswz[((kt*8 + nt)*64 + lane)] (short8) = W[n = nt*16 + (lane&15)]
//                                           [k = kt*32 + (lane>>4)*8 .. +7]
// so each wave's B-fragment load in the GEMM is a contiguous 1KB dwordx4 burst.
__global__ __launch_bounds__(256) void wconv_kernel(
    const float* __restrict__ W, unsigned short* __restrict__ Wswz) {
  int idx = blockIdx.x * 256 + threadIdx.x;   // 2048 short8 fragments
  if (idx >= DD * DD / 8) return;
  int lane = idx & 63;
  int nt   = (idx >> 6) & 7;
  int kt   = idx >> 9;
  int n = nt * 16 + (lane & 15);
  int k = kt * 32 + (lane >> 4) * 8;
  const float4* wrow = (const float4*)(W + (size_t)n * DD + k);
  float4 w0 = wrow[0];
  float4 w1 = wrow[1];
  unsigned int p0 = f2bf(w0.x) | ((unsigned int)f2bf(w0.y) << 16);
  unsigned int p1 = f2bf(w0.z) | ((unsigned int)f2bf(w0.w) << 16);
  unsigned int p2 = f2bf(w1.x) | ((unsigned int)f2bf(w1.y) << 16);
  unsigned int p3 = f2bf(w1.z) | ((unsigned int)f2bf(w1.w) << 16);
  ((uint4*)Wswz)[idx] = make_uint4(p0, p1, p2, p3);
}

// ---- Phase C: out[e,:] = (nm[src[e],:] - relu(ef[rev[e],:])) @ W^T + b ----
// LDS-free: A fragments gathered per-lane straight from global (each kt touches
// exactly one 128B line per edge row), B fragments from pre-swizzled Wswz (L2-hot).
// No __syncthreads, no bank conflicts; occupancy VGPR-limited at 4 blocks/CU.
__global__ __launch_bounds__(256, 4) void fused_gather_gemm_kernel(
    const float* __restrict__ ef, const float* __restrict__ nm,
    const unsigned short* __restrict__ Wswz, const float* __restrict__ bias,
    const int* __restrict__ eidx, const int* __restrict__ rev,
    float* __restrict__ out, int E) {
  const int tid  = threadIdx.x;
  const int lane = tid & 63;
  const int wave = tid >> 6;                  // 4 waves, 16 edges each
  const int col  = lane & 15;
  const int quad = lane >> 4;
  const int e0   = blockIdx.x * TILE_E + wave * 16;

  // this lane's A-row edge (same for all 4 quads; cache broadcasts)
  const int ea = e0 + col;
  int s = 0, rv = 0;
  if (ea < E) { s = eidx[ea]; rv = rev[ea]; }
  const float4* __restrict__ nmp = (const float4*)(nm + (size_t)s  * DD);
  const float4* __restrict__ efp = (const float4*)(ef + (size_t)rv * DD);
  const short8* __restrict__ wp  = (const short8*)Wswz + lane;

  f32x4 acc[8];
  #pragma unroll
  for (int i = 0; i < 8; ++i) acc[i] = (f32x4){0.f, 0.f, 0.f, 0.f};

  #pragma unroll
  for (int kt = 0; kt < 4; ++kt) {
    const int k4 = kt * 8 + quad * 2;         // float4 index: k = kt*32 + quad*8
    float4 a0 = nmp[k4];
    float4 a1 = nmp[k4 + 1];
    float4 m0 = efp[k4];
    float4 m1 = efp[k4 + 1];
    float x0 = a0.x - fmaxf(m0.x, 0.f);
    float x1 = a0.y - fmaxf(m0.y, 0.f);
    float x2 = a0.z - fmaxf(m0.z, 0.f);
    float x3 = a0.w - fmaxf(m0.w, 0.f);
    float x4 = a1.x - fmaxf(m1.x, 0.f);
    float x5 = a1.y - fmaxf(m1.y, 0.f);
    float x6 = a1.z - fmaxf(m1.z, 0.f);
    float x7 = a1.w - fmaxf(m1.w, 0.f);
    union { unsigned int u[4]; short8 s8; } cvt;
    cvt.u[0] = f2bf(x0) | ((unsigned int)f2bf(x1) << 16);
    cvt.u[1] = f2bf(x2) | ((unsigned int)f2bf(x3) << 16);
    cvt.u[2] = f2bf(x4) | ((unsigned int)f2bf(x5) << 16);
    cvt.u[3] = f2bf(x6) | ((unsigned int)f2bf(x7) << 16);
    short8 a = cvt.s8;
    #pragma unroll
    for (int nt = 0; nt < 8; ++nt) {
      short8 b = wp[(kt * 8 + nt) * 64];
      acc[nt] = __builtin_amdgcn_mfma_f32_16x16x32_bf16(a, b, acc[nt], 0, 0, 0);
    }
  }

  // epilogue: D[row=quad*4+r][col], +bias
  #pragma unroll
  for (int nt = 0; nt < 8; ++nt) {
    float bj = bias[nt * 16 + col];
    #pragma unroll
    for (int r = 0; r < 4; ++r) {
      int e = e0 + quad * 4 + r;
      if (e < E) out[(size_t)e * DD + nt * 16 + col] = acc[nt][r] + bj;
    }
  }
}

extern "C" void kernel_launch(void* const* d_in, const int* in_sizes, int n_in,
                              void* d_out, int out_size, void* d_ws, size_t ws_size,
                              hipStream_t stream) {
  const float* ef   = (const float*)d_in[0];
  const float* W    = (const float*)d_in[2];
  const float* bias = (const float*)d_in[3];
  const int*   eidx = (const int*)d_in[4];   // [2,E]: row0=src, row1=dest (int32 per harness)
  const int*   rev  = (const int*)d_in[5];   // [E]
  float*       out  = (float*)d_out;

  const int V = in_sizes[1];
  const int E = in_sizes[5];

  // workspace layout (256B-aligned slices)
  char* ws = (char*)d_ws;
  size_t o = 0;
  float* nm = (float*)(ws + o);            o += (size_t)V * DD * sizeof(float);
  o = (o + 255) & ~(size_t)255;
  int* cnt  = (int*)(ws + o);              o += (size_t)V * sizeof(int);
  o = (o + 255) & ~(size_t)255;
  int* off  = (int*)(ws + o);              o += (size_t)V * sizeof(int);
  o = (o + 255) & ~(size_t)255;
  int* cur  = (int*)(ws + o);              o += (size_t)V * sizeof(int);
  o = (o + 255) & ~(size_t)255;
  int* elist = (int*)(ws + o);             o += (size_t)E * sizeof(int);
  o = (o + 255) & ~(size_t)255;
  unsigned short* Wswz = (unsigned short*)(ws + o);

  hipMemsetAsync(cnt, 0, (size_t)V * sizeof(int), stream);

  int eb = (E + 255) / 256;
  hist_kernel<<<eb, 256, 0, stream>>>(eidx, cnt, E);
  scan_kernel<<<1, 1024, 0, stream>>>(cnt, off, cur, V);
  fill_kernel<<<eb, 256, 0, stream>>>(eidx, cur, elist, E);
  gather_sum_kernel<<<(V + 3) / 4, 256, 0, stream>>>(ef, off, cnt, elist, nm, V);
  wconv_kernel<<<(DD * DD / 8 + 255) / 256, 256, 0, stream>>>(W, Wswz);

  int nblocks = (E + TILE_E - 1) / TILE_E;
  fused_gather_gemm_kernel<<<nblocks, 256, 0, stream>>>(ef, nm, Wswz, bias, eidx, rev, out, E);
}

// Round 2
// 730.192 us; speedup vs baseline: 1.0659x; 1.0137x over previous
//
#include <hip/hip_runtime.h>

#define DD 128
#define TILE_E 64

typedef __attribute__((ext_vector_type(8))) short short8;
typedef __attribute__((ext_vector_type(4))) float f32x4;

__device__ __forceinline__ unsigned short f2bf(float f) {
  unsigned int u = __float_as_uint(f);
  u += 0x7FFF + ((u >> 16) & 1);   // RNE
  return (unsigned short)(u >> 16);
}

// ---- Phase A: build dest-sorted edge list (replaces 64M fp32 atomics) ----

__global__ __launch_bounds__(256) void hist_kernel(
    const int* __restrict__ eidx, int* __restrict__ cnt, int E) {
  int e = blockIdx.x * 256 + threadIdx.x;
  if (e < E) atomicAdd(&cnt[eidx[E + e]], 1);
}

// single-block exclusive scan over V counts -> off, and copy -> cur
__global__ __launch_bounds__(1024) void scan_kernel(
    const int* __restrict__ cnt, int* __restrict__ off, int* __restrict__ cur, int V) {
  __shared__ int s[1024];
  const int t = threadIdx.x;
  const int chunk = (V + 1023) / 1024;
  const int lo = t * chunk, hi = min(lo + chunk, V);
  int tot = 0;
  for (int v = lo; v < hi; ++v) tot += cnt[v];
  s[t] = tot;
  __syncthreads();
  // Hillis-Steele inclusive scan of thread totals
  for (int d = 1; d < 1024; d <<= 1) {
    int x = (t >= d) ? s[t - d] : 0;
    __syncthreads();
    s[t] += x;
    __syncthreads();
  }
  int run = (t > 0) ? s[t - 1] : 0;
  for (int v = lo; v < hi; ++v) {
    off[v] = run; cur[v] = run;
    run += cnt[v];
  }
}

__global__ __launch_bounds__(256) void fill_kernel(
    const int* __restrict__ eidx, int* __restrict__ cur,
    int* __restrict__ elist, int E) {
  int e = blockIdx.x * 256 + threadIdx.x;
  if (e < E) {
    int p = atomicAdd(&cur[eidx[E + e]], 1);
    elist[p] = e;
  }
}

// ---- Phase B: nm[v,:] = sum_{e: dest[e]=v} relu(ef[e,:])  (one wave per node) ----
// float4 loads, 2 rows per instruction (half-wave per row), 8 rows in flight;
// final half-combine via __shfl_xor(.,32).
__global__ __launch_bounds__(256) void gather_sum_kernel(
    const float* __restrict__ ef, const int* __restrict__ off,
    const int* __restrict__ cnt, const int* __restrict__ elist,
    float* __restrict__ nm, int V) {
  const int lane = threadIdx.x & 63;
  const int half = lane >> 5;        // 0: even rows, 1: odd rows
  const int l32  = lane & 31;        // float4 index within row
  const int v = blockIdx.x * 4 + (threadIdx.x >> 6);
  if (v >= V) return;
  const int base = off[v];
  const int deg  = cnt[v];
  f32x4 acc = (f32x4){0.f, 0.f, 0.f, 0.f};
  int j = 0;
  for (; j + 8 <= deg; j += 8) {
    int e0 = elist[base + j + 0 + half];
    int e1 = elist[base + j + 2 + half];
    int e2 = elist[base + j + 4 + half];
    int e3 = elist[base + j + 6 + half];
    float4 m0 = ((const float4*)(ef + (size_t)e0 * DD))[l32];
    float4 m1 = ((const float4*)(ef + (size_t)e1 * DD))[l32];
    float4 m2 = ((const float4*)(ef + (size_t)e2 * DD))[l32];
    float4 m3 = ((const float4*)(ef + (size_t)e3 * DD))[l32];
    acc[0] += fmaxf(m0.x, 0.f) + fmaxf(m1.x, 0.f) + fmaxf(m2.x, 0.f) + fmaxf(m3.x, 0.f);
    acc[1] += fmaxf(m0.y, 0.f) + fmaxf(m1.y, 0.f) + fmaxf(m2.y, 0.f) + fmaxf(m3.y, 0.f);
    acc[2] += fmaxf(m0.z, 0.f) + fmaxf(m1.z, 0.f) + fmaxf(m2.z, 0.f) + fmaxf(m3.z, 0.f);
    acc[3] += fmaxf(m0.w, 0.f) + fmaxf(m1.w, 0.f) + fmaxf(m2.w, 0.f) + fmaxf(m3.w, 0.f);
  }
  for (; j < deg; j += 2) {
    int idx = j + half;
    if (idx < deg) {
      int e = elist[base + idx];
      float4 m = ((const float4*)(ef + (size_t)e * DD))[l32];
      acc[0] += fmaxf(m.x, 0.f);
      acc[1] += fmaxf(m.y, 0.f);
      acc[2] += fmaxf(m.z, 0.f);
      acc[3] += fmaxf(m.w, 0.f);
    }
  }
  float4 tot;
  tot.x = acc[0] + __shfl_xor(acc[0], 32);
  tot.y = acc[1] + __shfl_xor(acc[1], 32);
  tot.z = acc[2] + __shfl_xor(acc[2], 32);
  tot.w = acc[3] + __shfl_xor(acc[3], 32);
  if (half == 0)
    ((float4*)(nm + (size_t)v * DD))[l32] = tot;
}

// ---- W -> bf16 fragment-major precompute (once per launch) ----
// Wswz[((kt*8 + nt)*64 + lane)] (short8) = W[n = nt*16 + (lane&15)]
//                                           [k = kt*32 + (lane>>4)*8 .. +7]
__global__ __launch_bounds__(256) void wconv_kernel(
    const float* __restrict__ W, unsigned short* __restrict__ Wswz) {
  int idx = blockIdx.x * 256 + threadIdx.x;   // 2048 short8 fragments
  if (idx >= DD * DD / 8) return;
  int lane = idx & 63;
  int nt   = (idx >> 6) & 7;
  int kt   = idx >> 9;
  int n = nt * 16 + (lane & 15);
  int k = kt * 32 + (lane >> 4) * 8;
  const float4* wrow = (const float4*)(W + (size_t)n * DD + k);
  float4 w0 = wrow[0];
  float4 w1 = wrow[1];
  unsigned int p0 = f2bf(w0.x) | ((unsigned int)f2bf(w0.y) << 16);
  unsigned int p1 = f2bf(w0.z) | ((unsigned int)f2bf(w0.w) << 16);
  unsigned int p2 = f2bf(w1.x) | ((unsigned int)f2bf(w1.y) << 16);
  unsigned int p3 = f2bf(w1.z) | ((unsigned int)f2bf(w1.w) << 16);
  ((uint4*)Wswz)[idx] = make_uint4(p0, p1, p2, p3);
}

// ---- Phase C: out[e,:] = (nm[src[e],:] - relu(ef[rev[e],:])) @ W^T + b ----
// LDS-free. Full A-prefetch: all 16 float4 gathers issued before any cvt/MFMA
// (one wait cluster per tile, ~16 loads in flight per wave). Non-temporal out
// stores keep ef resident in L3.
__global__ __launch_bounds__(256, 4) void fused_gather_gemm_kernel(
    const float* __restrict__ ef, const float* __restrict__ nm,
    const unsigned short* __restrict__ Wswz, const float* __restrict__ bias,
    const int* __restrict__ eidx, const int* __restrict__ rev,
    float* __restrict__ out, int E) {
  const int tid  = threadIdx.x;
  const int lane = tid & 63;
  const int wave = tid >> 6;                  // 4 waves, 16 edges each
  const int col  = lane & 15;
  const int quad = lane >> 4;
  const int e0   = blockIdx.x * TILE_E + wave * 16;

  const int ea = e0 + col;
  int s = 0, rv = 0;
  if (ea < E) { s = eidx[ea]; rv = rev[ea]; }
  const float4* __restrict__ nmp = (const float4*)(nm + (size_t)s  * DD);
  const float4* __restrict__ efp = (const float4*)(ef + (size_t)rv * DD);
  const short8* __restrict__ wp  = (const short8*)Wswz + lane;

  // prefetch ALL A-operand data: 8 nm + 8 ef float4s per lane
  float4 a[8], m[8];
  #pragma unroll
  for (int kt = 0; kt < 4; ++kt) {
    const int k4 = kt * 8 + quad * 2;         // float4 index: k = kt*32 + quad*8
    a[kt * 2]     = nmp[k4];
    a[kt * 2 + 1] = nmp[k4 + 1];
    m[kt * 2]     = efp[k4];
    m[kt * 2 + 1] = efp[k4 + 1];
  }

  f32x4 acc[8];
  #pragma unroll
  for (int i = 0; i < 8; ++i) acc[i] = (f32x4){0.f, 0.f, 0.f, 0.f};

  #pragma unroll
  for (int kt = 0; kt < 4; ++kt) {
    float4 a0 = a[kt * 2], a1 = a[kt * 2 + 1];
    float4 m0 = m[kt * 2], m1 = m[kt * 2 + 1];
    float x0 = a0.x - fmaxf(m0.x, 0.f);
    float x1 = a0.y - fmaxf(m0.y, 0.f);
    float x2 = a0.z - fmaxf(m0.z, 0.f);
    float x3 = a0.w - fmaxf(m0.w, 0.f);
    float x4 = a1.x - fmaxf(m1.x, 0.f);
    float x5 = a1.y - fmaxf(m1.y, 0.f);
    float x6 = a1.z - fmaxf(m1.z, 0.f);
    float x7 = a1.w - fmaxf(m1.w, 0.f);
    union { unsigned int u[4]; short8 s8; } cvt;
    cvt.u[0] = f2bf(x0) | ((unsigned int)f2bf(x1) << 16);
    cvt.u[1] = f2bf(x2) | ((unsigned int)f2bf(x3) << 16);
    cvt.u[2] = f2bf(x4) | ((unsigned int)f2bf(x5) << 16);
    cvt.u[3] = f2bf(x6) | ((unsigned int)f2bf(x7) << 16);
    short8 av = cvt.s8;
    #pragma unroll
    for (int nt = 0; nt < 8; ++nt) {
      short8 b = wp[(kt * 8 + nt) * 64];
      acc[nt] = __builtin_amdgcn_mfma_f32_16x16x32_bf16(av, b, acc[nt], 0, 0, 0);
    }
  }

  // epilogue: D[row=quad*4+r][col], +bias; non-temporal (out never re-read)
  #pragma unroll
  for (int nt = 0; nt < 8; ++nt) {
    float bj = bias[nt * 16 + col];
    #pragma unroll
    for (int r = 0; r < 4; ++r) {
      int e = e0 + quad * 4 + r;
      if (e < E)
        __builtin_nontemporal_store(acc[nt][r] + bj,
                                    &out[(size_t)e * DD + nt * 16 + col]);
    }
  }
}

extern "C" void kernel_launch(void* const* d_in, const int* in_sizes, int n_in,
                              void* d_out, int out_size, void* d_ws, size_t ws_size,
                              hipStream_t stream) {
  const float* ef   = (const float*)d_in[0];
  const float* W    = (const float*)d_in[2];
  const float* bias = (const float*)d_in[3];
  const int*   eidx = (const int*)d_in[4];   // [2,E]: row0=src, row1=dest (int32 per harness)
  const int*   rev  = (const int*)d_in[5];   // [E]
  float*       out  = (float*)d_out;

  const int V = in_sizes[1];
  const int E = in_sizes[5];

  // workspace layout (256B-aligned slices)
  char* ws = (char*)d_ws;
  size_t o = 0;
  float* nm = (float*)(ws + o);            o += (size_t)V * DD * sizeof(float);
  o = (o + 255) & ~(size_t)255;
  int* cnt  = (int*)(ws + o);              o += (size_t)V * sizeof(int);
  o = (o + 255) & ~(size_t)255;
  int* off  = (int*)(ws + o);              o += (size_t)V * sizeof(int);
  o = (o + 255) & ~(size_t)255;
  int* cur  = (int*)(ws + o);              o += (size_t)V * sizeof(int);
  o = (o + 255) & ~(size_t)255;
  int* elist = (int*)(ws + o);             o += (size_t)E * sizeof(int);
  o = (o + 255) & ~(size_t)255;
  unsigned short* Wswz = (unsigned short*)(ws + o);

  hipMemsetAsync(cnt, 0, (size_t)V * sizeof(int), stream);

  int eb = (E + 255) / 256;
  hist_kernel<<<eb, 256, 0, stream>>>(eidx, cnt, E);
  scan_kernel<<<1, 1024, 0, stream>>>(cnt, off, cur, V);
  fill_kernel<<<eb, 256, 0, stream>>>(eidx, cur, elist, E);
  gather_sum_kernel<<<(V + 3) / 4, 256, 0, stream>>>(ef, off, cnt, elist, nm, V);
  wconv_kernel<<<(DD * DD / 8 + 255) / 256, 256, 0, stream>>>(W, Wswz);

  int nblocks = (E + TILE_E - 1) / TILE_E;
  fused_gather_gemm_kernel<<<nblocks, 256, 0, stream>>>(ef, nm, Wswz, bias, eidx, rev, out, E);
}

// Round 3
// 710.886 us; speedup vs baseline: 1.0948x; 1.0272x over previous
//
#include <hip/hip_runtime.h>

#define DD 128
#define TILE_E 64

typedef __attribute__((ext_vector_type(8))) short short8;
typedef __attribute__((ext_vector_type(4))) float f32x4;

__device__ __forceinline__ unsigned short f2bf(float f) {
  unsigned int u = __float_as_uint(f);
  u += 0x7FFF + ((u >> 16) & 1);   // RNE
  return (unsigned short)(u >> 16);
}

// ---- Phase A: build dest-sorted edge list (replaces 64M fp32 atomics) ----

__global__ __launch_bounds__(256) void hist_kernel(
    const int* __restrict__ eidx, int* __restrict__ cnt, int E) {
  int e = blockIdx.x * 256 + threadIdx.x;
  if (e < E) atomicAdd(&cnt[eidx[E + e]], 1);
}

// single-block exclusive scan over V counts -> off, and copy -> cur
__global__ __launch_bounds__(1024) void scan_kernel(
    const int* __restrict__ cnt, int* __restrict__ off, int* __restrict__ cur, int V) {
  __shared__ int s[1024];
  const int t = threadIdx.x;
  const int chunk = (V + 1023) / 1024;
  const int lo = t * chunk, hi = min(lo + chunk, V);
  int tot = 0;
  for (int v = lo; v < hi; ++v) tot += cnt[v];
  s[t] = tot;
  __syncthreads();
  // Hillis-Steele inclusive scan of thread totals
  for (int d = 1; d < 1024; d <<= 1) {
    int x = (t >= d) ? s[t - d] : 0;
    __syncthreads();
    s[t] += x;
    __syncthreads();
  }
  int run = (t > 0) ? s[t - 1] : 0;
  for (int v = lo; v < hi; ++v) {
    off[v] = run; cur[v] = run;
    run += cnt[v];
  }
}

__global__ __launch_bounds__(256) void fill_kernel(
    const int* __restrict__ eidx, int* __restrict__ cur,
    int* __restrict__ elist, int E) {
  int e = blockIdx.x * 256 + threadIdx.x;
  if (e < E) {
    int p = atomicAdd(&cur[eidx[E + e]], 1);
    elist[p] = e;
  }
}

// ---- Phase B: nm[v,:] = sum_{e: dest[e]=v} relu(ef[e,:])  (one wave per node) ----
// float4 loads, 2 rows per instruction (half-wave per row), 8 rows per group.
// Software-pipelined: next group's elist indices issued before this group's row
// loads; sched_barrier(0) pins the load cluster ahead of the accumulate so the
// compiler cannot re-serialize (4 row loads + 4 idx loads in flight).
__global__ __launch_bounds__(256) void gather_sum_kernel(
    const float* __restrict__ ef, const int* __restrict__ off,
    const int* __restrict__ cnt, const int* __restrict__ elist,
    float* __restrict__ nm, int V) {
  const int lane = threadIdx.x & 63;
  const int half = lane >> 5;        // 0: even rows, 1: odd rows
  const int l32  = lane & 31;        // float4 index within row
  const int v = blockIdx.x * 4 + (threadIdx.x >> 6);
  if (v >= V) return;
  const int base = off[v];
  const int deg  = cnt[v];
  f32x4 acc = (f32x4){0.f, 0.f, 0.f, 0.f};
  int j = 0;
  int i0 = 0, i1 = 0, i2 = 0, i3 = 0;
  if (j + 8 <= deg) {
    i0 = elist[base + j + 0 + half];
    i1 = elist[base + j + 2 + half];
    i2 = elist[base + j + 4 + half];
    i3 = elist[base + j + 6 + half];
  }
  while (j + 8 <= deg) {
    const int jn = j + 8;
    int n0 = 0, n1 = 0, n2 = 0, n3 = 0;
    if (jn + 8 <= deg) {             // wave-uniform branch (deg uniform per wave)
      n0 = elist[base + jn + 0 + half];
      n1 = elist[base + jn + 2 + half];
      n2 = elist[base + jn + 4 + half];
      n3 = elist[base + jn + 6 + half];
    }
    float4 m0 = ((const float4*)(ef + (size_t)i0 * DD))[l32];
    float4 m1 = ((const float4*)(ef + (size_t)i1 * DD))[l32];
    float4 m2 = ((const float4*)(ef + (size_t)i2 * DD))[l32];
    float4 m3 = ((const float4*)(ef + (size_t)i3 * DD))[l32];
    __builtin_amdgcn_sched_barrier(0);
    acc[0] += fmaxf(m0.x, 0.f) + fmaxf(m1.x, 0.f) + fmaxf(m2.x, 0.f) + fmaxf(m3.x, 0.f);
    acc[1] += fmaxf(m0.y, 0.f) + fmaxf(m1.y, 0.f) + fmaxf(m2.y, 0.f) + fmaxf(m3.y, 0.f);
    acc[2] += fmaxf(m0.z, 0.f) + fmaxf(m1.z, 0.f) + fmaxf(m2.z, 0.f) + fmaxf(m3.z, 0.f);
    acc[3] += fmaxf(m0.w, 0.f) + fmaxf(m1.w, 0.f) + fmaxf(m2.w, 0.f) + fmaxf(m3.w, 0.f);
    j = jn; i0 = n0; i1 = n1; i2 = n2; i3 = n3;
  }
  for (; j < deg; j += 2) {
    int idx = j + half;
    if (idx < deg) {
      int e = elist[base + idx];
      float4 m = ((const float4*)(ef + (size_t)e * DD))[l32];
      acc[0] += fmaxf(m.x, 0.f);
      acc[1] += fmaxf(m.y, 0.f);
      acc[2] += fmaxf(m.z, 0.f);
      acc[3] += fmaxf(m.w, 0.f);
    }
  }
  float4 tot;
  tot.x = acc[0] + __shfl_xor(acc[0], 32);
  tot.y = acc[1] + __shfl_xor(acc[1], 32);
  tot.z = acc[2] + __shfl_xor(acc[2], 32);
  tot.w = acc[3] + __shfl_xor(acc[3], 32);
  if (half == 0)
    ((float4*)(nm + (size_t)v * DD))[l32] = tot;
}

// ---- W -> bf16 fragment-major precompute (once per launch) ----
// Wswz[((kt*8 + nt)*64 + lane)] (short8) = W[n = nt*16 + (lane&15)]
//                                           [k = kt*32 + (lane>>4)*8 .. +7]
__global__ __launch_bounds__(256) void wconv_kernel(
    const float* __restrict__ W, unsigned short* __restrict__ Wswz) {
  int idx = blockIdx.x * 256 + threadIdx.x;   // 2048 short8 fragments
  if (idx >= DD * DD / 8) return;
  int lane = idx & 63;
  int nt   = (idx >> 6) & 7;
  int kt   = idx >> 9;
  int n = nt * 16 + (lane & 15);
  int k = kt * 32 + (lane >> 4) * 8;
  const float4* wrow = (const float4*)(W + (size_t)n * DD + k);
  float4 w0 = wrow[0];
  float4 w1 = wrow[1];
  unsigned int p0 = f2bf(w0.x) | ((unsigned int)f2bf(w0.y) << 16);
  unsigned int p1 = f2bf(w0.z) | ((unsigned int)f2bf(w0.w) << 16);
  unsigned int p2 = f2bf(w1.x) | ((unsigned int)f2bf(w1.y) << 16);
  unsigned int p3 = f2bf(w1.z) | ((unsigned int)f2bf(w1.w) << 16);
  ((uint4*)Wswz)[idx] = make_uint4(p0, p1, p2, p3);
}

// ---- Phase C: out[e,:] = (nm[src[e],:] - relu(ef[rev[e],:])) @ W^T + b ----
// LDS-free. All 16 A-operand float4 gathers are issued as one cluster and
// PINNED with sched_barrier(0) so the compiler cannot sink them back into the
// kt-loop (round-2 failure mode: VGPR=36 proved re-serialization). First MFMA
// waits at vmcnt(12); ~16 loads in flight per wave.
__global__ __launch_bounds__(256, 4) void fused_gather_gemm_kernel(
    const float* __restrict__ ef, const float* __restrict__ nm,
    const unsigned short* __restrict__ Wswz, const float* __restrict__ bias,
    const int* __restrict__ eidx, const int* __restrict__ rev,
    float* __restrict__ out, int E) {
  const int tid  = threadIdx.x;
  const int lane = tid & 63;
  const int wave = tid >> 6;                  // 4 waves, 16 edges each
  const int col  = lane & 15;
  const int quad = lane >> 4;
  const int e0   = blockIdx.x * TILE_E + wave * 16;

  const int ea = e0 + col;
  int s = 0, rv = 0;
  if (ea < E) { s = eidx[ea]; rv = rev[ea]; }
  const float4* __restrict__ nmp = (const float4*)(nm + (size_t)s  * DD);
  const float4* __restrict__ efp = (const float4*)(ef + (size_t)rv * DD);
  const short8* __restrict__ wp  = (const short8*)Wswz + lane;

  // issue ALL A-operand loads, interleaved a,a,m,m per kt
  float4 a[8], m[8];
  #pragma unroll
  for (int kt = 0; kt < 4; ++kt) {
    const int k4 = kt * 8 + quad * 2;         // float4 index: k = kt*32 + quad*8
    a[kt * 2]     = nmp[k4];
    a[kt * 2 + 1] = nmp[k4 + 1];
    m[kt * 2]     = efp[k4];
    m[kt * 2 + 1] = efp[k4 + 1];
  }
  __builtin_amdgcn_sched_barrier(0);          // loads may NOT sink past here

  f32x4 acc[8];
  #pragma unroll
  for (int i = 0; i < 8; ++i) acc[i] = (f32x4){0.f, 0.f, 0.f, 0.f};

  #pragma unroll
  for (int kt = 0; kt < 4; ++kt) {
    float4 a0 = a[kt * 2], a1 = a[kt * 2 + 1];
    float4 m0 = m[kt * 2], m1 = m[kt * 2 + 1];
    float x0 = a0.x - fmaxf(m0.x, 0.f);
    float x1 = a0.y - fmaxf(m0.y, 0.f);
    float x2 = a0.z - fmaxf(m0.z, 0.f);
    float x3 = a0.w - fmaxf(m0.w, 0.f);
    float x4 = a1.x - fmaxf(m1.x, 0.f);
    float x5 = a1.y - fmaxf(m1.y, 0.f);
    float x6 = a1.z - fmaxf(m1.z, 0.f);
    float x7 = a1.w - fmaxf(m1.w, 0.f);
    union { unsigned int u[4]; short8 s8; } cvt;
    cvt.u[0] = f2bf(x0) | ((unsigned int)f2bf(x1) << 16);
    cvt.u[1] = f2bf(x2) | ((unsigned int)f2bf(x3) << 16);
    cvt.u[2] = f2bf(x4) | ((unsigned int)f2bf(x5) << 16);
    cvt.u[3] = f2bf(x6) | ((unsigned int)f2bf(x7) << 16);
    short8 av = cvt.s8;
    #pragma unroll
    for (int nt = 0; nt < 8; ++nt) {
      short8 b = wp[(kt * 8 + nt) * 64];
      acc[nt] = __builtin_amdgcn_mfma_f32_16x16x32_bf16(av, b, acc[nt], 0, 0, 0);
    }
  }

  // epilogue: D[row=quad*4+r][col], +bias; non-temporal (out never re-read)
  #pragma unroll
  for (int nt = 0; nt < 8; ++nt) {
    float bj = bias[nt * 16 + col];
    #pragma unroll
    for (int r = 0; r < 4; ++r) {
      int e = e0 + quad * 4 + r;
      if (e < E)
        __builtin_nontemporal_store(acc[nt][r] + bj,
                                    &out[(size_t)e * DD + nt * 16 + col]);
    }
  }
}

extern "C" void kernel_launch(void* const* d_in, const int* in_sizes, int n_in,
                              void* d_out, int out_size, void* d_ws, size_t ws_size,
                              hipStream_t stream) {
  const float* ef   = (const float*)d_in[0];
  const float* W    = (const float*)d_in[2];
  const float* bias = (const float*)d_in[3];
  const int*   eidx = (const int*)d_in[4];   // [2,E]: row0=src, row1=dest (int32 per harness)
  const int*   rev  = (const int*)d_in[5];   // [E]
  float*       out  = (float*)d_out;

  const int V = in_sizes[1];
  const int E = in_sizes[5];

  // workspace layout (256B-aligned slices)
  char* ws = (char*)d_ws;
  size_t o = 0;
  float* nm = (float*)(ws + o);            o += (size_t)V * DD * sizeof(float);
  o = (o + 255) & ~(size_t)255;
  int* cnt  = (int*)(ws + o);              o += (size_t)V * sizeof(int);
  o = (o + 255) & ~(size_t)255;
  int* off  = (int*)(ws + o);              o += (size_t)V * sizeof(int);
  o = (o + 255) & ~(size_t)255;
  int* cur  = (int*)(ws + o);              o += (size_t)V * sizeof(int);
  o = (o + 255) & ~(size_t)255;
  int* elist = (int*)(ws + o);             o += (size_t)E * sizeof(int);
  o = (o + 255) & ~(size_t)255;
  unsigned short* Wswz = (unsigned short*)(ws + o);

  hipMemsetAsync(cnt, 0, (size_t)V * sizeof(int), stream);

  int eb = (E + 255) / 256;
  hist_kernel<<<eb, 256, 0, stream>>>(eidx, cnt, E);
  scan_kernel<<<1, 1024, 0, stream>>>(cnt, off, cur, V);
  fill_kernel<<<eb, 256, 0, stream>>>(eidx, cur, elist, E);
  gather_sum_kernel<<<(V + 3) / 4, 256, 0, stream>>>(ef, off, cnt, elist, nm, V);
  wconv_kernel<<<(DD * DD / 8 + 255) / 256, 256, 0, stream>>>(W, Wswz);

  int nblocks = (E + TILE_E - 1) / TILE_E;
  fused_gather_gemm_kernel<<<nblocks, 256, 0, stream>>>(ef, nm, Wswz, bias, eidx, rev, out, E);
}